// Round 14
// baseline (53.358 us; speedup 1.0000x reference)
//
#include <hip/hip_runtime.h>
#include <cfloat>

typedef float f32x16 __attribute__((ext_vector_type(16)));
typedef float f32x8  __attribute__((ext_vector_type(8)));
typedef float f32x4v __attribute__((ext_vector_type(4)));
typedef float f32x2  __attribute__((ext_vector_type(2)));
typedef short s16x8  __attribute__((ext_vector_type(8)));

// Problem constants
constexpr int B = 4, N = 8192;
constexpr int JT    = 16;            // 32-col j-tiles per wave (output side)
constexpr int JSTR  = N / (32 * JT); // 16 j-strips
constexpr int IGRP  = 32;            // 256-row i-groups (block granularity)
constexpr int NSEG  = 2 * B;         // 8 (dir,b) segments

__device__ __forceinline__ unsigned short f2bf(float x) {   // RNE bf16
    unsigned int u = __float_as_uint(x);
    u += 0x7fffu + ((u >> 16) & 1u);
    return (unsigned short)(u >> 16);
}
__device__ __forceinline__ float bf2f(unsigned short h) {
    return __uint_as_float((unsigned int)h << 16);
}

// min over all 16 lanes-local C values, via packed-min halving tree
__device__ __forceinline__ float vmin16(f32x16 v) {
    f32x8 a = __builtin_shufflevector(v, v, 0, 1, 2, 3, 4, 5, 6, 7);
    f32x8 b = __builtin_shufflevector(v, v, 8, 9, 10, 11, 12, 13, 14, 15);
    f32x8 m8 = __builtin_elementwise_min(a, b);
    f32x4v c = __builtin_shufflevector(m8, m8, 0, 1, 2, 3);
    f32x4v d = __builtin_shufflevector(m8, m8, 4, 5, 6, 7);
    f32x4v m4 = __builtin_elementwise_min(c, d);
    f32x2 e = __builtin_shufflevector(m4, m4, 0, 1);
    f32x2 f = __builtin_shufflevector(m4, m4, 2, 3);
    f32x2 m2 = __builtin_elementwise_min(e, f);
    return fminf(m2.x, m2.y);
}

// Pack each point into BOTH operand forms (validated slot plan, R7-R13):
//   A-form row: [-2xh,-2yh,-2zh, -2xl,-2yl,-2zl, -2xh,-2yh | -2zh, 1, 1, nh, nl, 0,0,0]
//   B-form col: [  xh,  yh,  zh,   xh,  yh,  zh,   xl,  yl |   zl, nh, nl, 1, 1, 0,0,0]
// => MFMA c = nA + nB - 2*a.b (squared distance; ll term dropped, err ~1e-3)
// Fragment layout (32x32x16): lane holds (row|col)=lane&31, k = 8*(lane>>5)+kk.
__global__ __launch_bounds__(256) void pack_kernel(
        const float* __restrict__ pred, const float* __restrict__ gt,
        uint4* __restrict__ Aform, uint4* __restrict__ Bform) {
    int id    = blockIdx.x * 256 + threadIdx.x;  // [0, 131072)
    int cloud = id >> 16;                        // 0 = pred, 1 = gt
    int rem   = id & 65535;
    int b     = rem >> 14;
    int t2    = rem & 16383;
    int blk   = t2 >> 6;                         // 32-point block [0,256)
    int lane  = t2 & 63;
    int h     = lane >> 5;
    int row   = blk * 32 + (lane & 31);

    const float* s = (cloud ? gt : pred) + ((size_t)b * N + row) * 3;
    float x = s[0], y = s[1], z = s[2];
    unsigned short xh = f2bf(x), yh = f2bf(y), zh = f2bf(z);
    float xl = x - bf2f(xh), yl = y - bf2f(yh), zl = z - bf2f(zh);
    float n = fmaf(x, x, fmaf(y, y, z * z));
    unsigned short nh = f2bf(n);
    unsigned short nl = f2bf(n - bf2f(nh));
    const unsigned short ONE = 0x3F80;

    unsigned short wa[8], wb[8];
    unsigned short mxh = f2bf(-2.f * bf2f(xh));
    unsigned short myh = f2bf(-2.f * bf2f(yh));
    unsigned short mzh = f2bf(-2.f * bf2f(zh));
    if (h == 0) {
        wa[0] = mxh; wa[1] = myh; wa[2] = mzh;
        wa[3] = f2bf(-2.f * xl); wa[4] = f2bf(-2.f * yl); wa[5] = f2bf(-2.f * zl);
        wa[6] = mxh; wa[7] = myh;
        wb[0] = xh; wb[1] = yh; wb[2] = zh;
        wb[3] = xh; wb[4] = yh; wb[5] = zh;
        wb[6] = f2bf(xl); wb[7] = f2bf(yl);
    } else {
        wa[0] = mzh; wa[1] = ONE; wa[2] = ONE; wa[3] = nh; wa[4] = nl;
        wa[5] = 0; wa[6] = 0; wa[7] = 0;
        wb[0] = f2bf(zl); wb[1] = nh; wb[2] = nl; wb[3] = ONE; wb[4] = ONE;
        wb[5] = 0; wb[6] = 0; wb[7] = 0;
    }
    uint4 oa, ob;
    oa.x = (unsigned)wa[0] | ((unsigned)wa[1] << 16);
    oa.y = (unsigned)wa[2] | ((unsigned)wa[3] << 16);
    oa.z = (unsigned)wa[4] | ((unsigned)wa[5] << 16);
    oa.w = (unsigned)wa[6] | ((unsigned)wa[7] << 16);
    ob.x = (unsigned)wb[0] | ((unsigned)wb[1] << 16);
    ob.y = (unsigned)wb[2] | ((unsigned)wb[3] << 16);
    ob.z = (unsigned)wb[4] | ((unsigned)wb[5] << 16);
    ob.w = (unsigned)wb[6] | ((unsigned)wb[7] << 16);
    size_t off = (((size_t)cloud * B + b) * 256 + blk) * 64 + lane;
    Aform[off] = oa;
    Bform[off] = ob;
}

// Block = 4 waves x 64-row strips = 256 rows, sharing one 512-col B-tile
// (16 frags, LDS-staged). Per jt: 2 MFMA chains (IB=2 keeps VGPR ~90,
// R12/R13 lesson), packed-min combine+tree (v_pk_min_f32), and both lane
// halves write partial col-mins to scm LDS (no shuffle, no global store in
// loop). Post-loop: combine scm's 8 rows -> one 512-col write at i-group
// granularity (part = 4 MB, 2x less reduce traffic).
__global__ __launch_bounds__(256) void chamfer_mfma(
        const uint4* __restrict__ Aform, const uint4* __restrict__ Bform,
        unsigned short* __restrict__ part) {
    int bid = blockIdx.x;
    int js  = bid & (JSTR - 1);        // fastest: consecutive blocks share A panel
    int is4 = (bid >> 4) & (IGRP - 1);
    int b   = (bid >> 9) & 3;
    int dir = bid >> 11;               // 0: minimize over pred; 1: over gt
    int Acl = dir;                     // A-side cloud (rows, minimized over)
    int Bcl = dir ^ 1;                 // B-side cloud (cols, output)

    int w    = threadIdx.x >> 6;
    int lane = threadIdx.x & 63;
    int is   = is4 * 4 + w;            // [0,128): this wave's 64-row strip

    __shared__ uint4 sb[JT * 64];      // 16 KB B-tile
    __shared__ float scm[8][JT * 32];  // 16 KB partial col-mins

    const uint4* bblk = Bform + (((size_t)Bcl * B + b) * 256 + js * JT) * 64;
#pragma unroll
    for (int t = 0; t < 4; ++t)
        sb[threadIdx.x + t * 256] = bblk[threadIdx.x + t * 256];

    // Per-wave A fragments (2 x 32-row blocks), issued before the barrier.
    const uint4* ablk = Aform + (((size_t)Acl * B + b) * 256 + is * 2) * 64 + lane;
    s16x8 a0 = __builtin_bit_cast(s16x8, ablk[0]);
    s16x8 a1 = __builtin_bit_cast(s16x8, ablk[64]);

    __syncthreads();

    const f32x16 zc = {};
    int srow = w * 2 + (lane >> 5);    // [0,8): which partial row this half-wave owns
    int scol = lane & 31;

    s16x8 bnext = __builtin_bit_cast(s16x8, sb[lane]);   // jt=0 fragment
#pragma unroll 1
    for (int jt = 0; jt < JT; ++jt) {
        s16x8 bfr = bnext;
        if (jt + 1 < JT)
            bnext = __builtin_bit_cast(s16x8, sb[(jt + 1) * 64 + lane]);

        f32x16 c0 = __builtin_amdgcn_mfma_f32_32x32x16_bf16(a0, bfr, zc, 0, 0, 0);
        f32x16 c1 = __builtin_amdgcn_mfma_f32_32x32x16_bf16(a1, bfr, zc, 0, 0, 0);
        f32x16 cm = __builtin_elementwise_min(c0, c1);   // 8 v_pk_min_f32
        scm[srow][jt * 32 + scol] = vmin16(cm);          // bank-clean (2-way)
    }
    __syncthreads();

    // Combine the 8 partial rows -> 512 col-mins of this 256-row i-group.
    unsigned short* po = part + (((size_t)dir * B + b) * IGRP + is4) * N + js * (JT * 32);
#pragma unroll
    for (int t = 0; t < 2; ++t) {
        int col = threadIdx.x + t * 256;
        float v = scm[0][col];
#pragma unroll
        for (int q = 1; q < 8; ++q) v = fminf(v, scm[q][col]);
        po[col] = f2bf(v);
    }
}

// 256 blocks: seg = bk>>5; min over 32 i-groups -> block sum/max partials.
__global__ __launch_bounds__(256) void reduce1(
        const unsigned short* __restrict__ part,
        float* __restrict__ bsum, float* __restrict__ bmax) {
    int bk  = blockIdx.x;
    int seg = bk >> 5;                 // 0..7
    int idx = (bk & 31) * 256 + threadIdx.x;
    const unsigned short* base = part + (size_t)seg * IGRP * N + idx;
    float v = FLT_MAX;
#pragma unroll 8
    for (int s = 0; s < IGRP; ++s)
        v = fminf(v, bf2f(base[(size_t)s * N]));
    __shared__ float ssum[256], smax[256];
    ssum[threadIdx.x] = v;
    smax[threadIdx.x] = v;
    __syncthreads();
    for (int st = 128; st > 0; st >>= 1) {
        if (threadIdx.x < st) {
            ssum[threadIdx.x] += ssum[threadIdx.x + st];
            smax[threadIdx.x] = fmaxf(smax[threadIdx.x], smax[threadIdx.x + st]);
        }
        __syncthreads();
    }
    if (threadIdx.x == 0) { bsum[bk] = ssum[0]; bmax[bk] = smax[0]; }
}

// Combine 256 block partials. Blocks [seg*32, seg*32+32) belong to segment seg.
__global__ __launch_bounds__(256) void final_combine(
        const float* __restrict__ bsum, const float* __restrict__ bmax,
        float* __restrict__ out) {
    int t = threadIdx.x;
    __shared__ float ss[256], sm[256];
    ss[t] = bsum[t];
    sm[t] = bmax[t];
    __syncthreads();
    for (int st = 128; st > 0; st >>= 1) {
        if (t < st) ss[t] += ss[t + st];
        __syncthreads();
    }
    for (int st = 16; st > 0; st >>= 1) {
        if ((t & 31) < st) sm[t] = fmaxf(sm[t], sm[t + st]);
        __syncthreads();
    }
    if (t == 0) {
        float hsum = 0.f;
#pragma unroll
        for (int k = 0; k < NSEG; ++k) hsum += sm[k * 32];
        out[0] = ss[0] / (float)(B * N);   // chamfer
        out[1] = hsum / (float)B;          // hausdorff
    }
}

extern "C" void kernel_launch(void* const* d_in, const int* in_sizes, int n_in,
                              void* d_out, int out_size, void* d_ws, size_t ws_size,
                              hipStream_t stream) {
    const float* pred = (const float*)d_in[0];
    const float* gt   = (const float*)d_in[1];
    float* out = (float*)d_out;

    char* p = (char*)d_ws;
    uint4* Aform = (uint4*)p;  p += (size_t)2 * B * 256 * 64 * 16;   // 2 MB
    uint4* Bform = (uint4*)p;  p += (size_t)2 * B * 256 * 64 * 16;   // 2 MB
    unsigned short* part = (unsigned short*)p;
    p += (size_t)2 * B * IGRP * N * 2;                               // 4 MB
    float* bsum = (float*)p;   p += 256 * 4;
    float* bmax = (float*)p;

    pack_kernel<<<512, 256, 0, stream>>>(pred, gt, Aform, Bform);
    // blocks: dir(2) x b(4) x is4(32) x js(16) = 4096, 4 waves each
    chamfer_mfma<<<4096, 256, 0, stream>>>(Aform, Bform, part);
    reduce1<<<256, 256, 0, stream>>>(part, bsum, bmax);
    final_combine<<<1, 256, 0, stream>>>(bsum, bmax, out);
}

// Round 15
// 50.137 us; speedup vs baseline: 1.0643x; 1.0643x over previous
//
#include <hip/hip_runtime.h>
#include <cfloat>

typedef float f32x16 __attribute__((ext_vector_type(16)));
typedef float f32x8  __attribute__((ext_vector_type(8)));
typedef float f32x4v __attribute__((ext_vector_type(4)));
typedef float f32x2  __attribute__((ext_vector_type(2)));
typedef short s16x8  __attribute__((ext_vector_type(8)));

// Problem constants
constexpr int B = 4, N = 8192;
constexpr int IB   = 4;              // 32-row i-blocks per wave (minimized-over side)
constexpr int JT   = 8;              // 32-col j-tiles per wave (output side)
constexpr int ISTR = N / (32 * IB);  // 64 i-strips
constexpr int JSTR = N / (32 * JT);  // 32 j-strips
constexpr int NSEG = 2 * B;          // 8 (dir,b) segments

__device__ __forceinline__ unsigned short f2bf(float x) {   // RNE bf16
    unsigned int u = __float_as_uint(x);
    u += 0x7fffu + ((u >> 16) & 1u);
    return (unsigned short)(u >> 16);
}
__device__ __forceinline__ float bf2f(unsigned short h) {
    return __uint_as_float((unsigned int)h << 16);
}

// min over the 16 lane-local C values via packed-min halving tree (v_pk_min_f32)
__device__ __forceinline__ float vmin16(f32x16 v) {
    f32x8 a = __builtin_shufflevector(v, v, 0, 1, 2, 3, 4, 5, 6, 7);
    f32x8 b = __builtin_shufflevector(v, v, 8, 9, 10, 11, 12, 13, 14, 15);
    f32x8 m8 = __builtin_elementwise_min(a, b);
    f32x4v c = __builtin_shufflevector(m8, m8, 0, 1, 2, 3);
    f32x4v d = __builtin_shufflevector(m8, m8, 4, 5, 6, 7);
    f32x4v m4 = __builtin_elementwise_min(c, d);
    f32x2 e = __builtin_shufflevector(m4, m4, 0, 1);
    f32x2 f = __builtin_shufflevector(m4, m4, 2, 3);
    f32x2 m2 = __builtin_elementwise_min(e, f);
    return fminf(m2.x, m2.y);
}

// Pack each point into BOTH operand forms (validated slot plan, R7-R14):
//   A-form row: [-2xh,-2yh,-2zh, -2xl,-2yl,-2zl, -2xh,-2yh | -2zh, 1, 1, nh, nl, 0,0,0]
//   B-form col: [  xh,  yh,  zh,   xh,  yh,  zh,   xl,  yl |   zl, nh, nl, 1, 1, 0,0,0]
// => MFMA c = nA + nB - 2*a.b (squared distance; ll term dropped, err ~1e-3)
// Fragment layout (32x32x16): lane holds (row|col)=lane&31, k = 8*(lane>>5)+kk.
__global__ __launch_bounds__(256) void pack_kernel(
        const float* __restrict__ pred, const float* __restrict__ gt,
        uint4* __restrict__ Aform, uint4* __restrict__ Bform) {
    int id    = blockIdx.x * 256 + threadIdx.x;  // [0, 131072)
    int cloud = id >> 16;                        // 0 = pred, 1 = gt
    int rem   = id & 65535;
    int b     = rem >> 14;
    int t2    = rem & 16383;
    int blk   = t2 >> 6;                         // 32-point block [0,256)
    int lane  = t2 & 63;
    int h     = lane >> 5;
    int row   = blk * 32 + (lane & 31);

    const float* s = (cloud ? gt : pred) + ((size_t)b * N + row) * 3;
    float x = s[0], y = s[1], z = s[2];
    unsigned short xh = f2bf(x), yh = f2bf(y), zh = f2bf(z);
    float xl = x - bf2f(xh), yl = y - bf2f(yh), zl = z - bf2f(zh);
    float n = fmaf(x, x, fmaf(y, y, z * z));
    unsigned short nh = f2bf(n);
    unsigned short nl = f2bf(n - bf2f(nh));
    const unsigned short ONE = 0x3F80;

    unsigned short wa[8], wb[8];
    unsigned short mxh = f2bf(-2.f * bf2f(xh));
    unsigned short myh = f2bf(-2.f * bf2f(yh));
    unsigned short mzh = f2bf(-2.f * bf2f(zh));
    if (h == 0) {
        wa[0] = mxh; wa[1] = myh; wa[2] = mzh;
        wa[3] = f2bf(-2.f * xl); wa[4] = f2bf(-2.f * yl); wa[5] = f2bf(-2.f * zl);
        wa[6] = mxh; wa[7] = myh;
        wb[0] = xh; wb[1] = yh; wb[2] = zh;
        wb[3] = xh; wb[4] = yh; wb[5] = zh;
        wb[6] = f2bf(xl); wb[7] = f2bf(yl);
    } else {
        wa[0] = mzh; wa[1] = ONE; wa[2] = ONE; wa[3] = nh; wa[4] = nl;
        wa[5] = 0; wa[6] = 0; wa[7] = 0;
        wb[0] = f2bf(zl); wb[1] = nh; wb[2] = nl; wb[3] = ONE; wb[4] = ONE;
        wb[5] = 0; wb[6] = 0; wb[7] = 0;
    }
    uint4 oa, ob;
    oa.x = (unsigned)wa[0] | ((unsigned)wa[1] << 16);
    oa.y = (unsigned)wa[2] | ((unsigned)wa[3] << 16);
    oa.z = (unsigned)wa[4] | ((unsigned)wa[5] << 16);
    oa.w = (unsigned)wa[6] | ((unsigned)wa[7] << 16);
    ob.x = (unsigned)wb[0] | ((unsigned)wb[1] << 16);
    ob.y = (unsigned)wb[2] | ((unsigned)wb[3] << 16);
    ob.z = (unsigned)wb[4] | ((unsigned)wb[5] << 16);
    ob.w = (unsigned)wb[6] | ((unsigned)wb[7] << 16);
    size_t off = (((size_t)cloud * B + b) * 256 + blk) * 64 + lane;
    Aform[off] = oa;
    Bform[off] = ob;
}

// Reduce one jt's 4 MFMA tiles -> col-min + store (packed-min tree).
#define REDUCE_STORE(C0, C1, C2, C3, JTIDX) do {                         \
    f32x16 m01_ = __builtin_elementwise_min(C0, C1);                     \
    f32x16 m23_ = __builtin_elementwise_min(C2, C3);                     \
    f32x16 mm_  = __builtin_elementwise_min(m01_, m23_);                 \
    float cm_ = vmin16(mm_);                                             \
    float colmin_ = fminf(cm_, __shfl_xor(cm_, 32));                     \
    if (lane < 32) po[(JTIDX) * 32 + lane] = f2bf(colmin_);              \
} while (0)

// Block = 4 waves sharing one LDS-staged B-tile; wave w owns i-strip is4*4+w.
// SOFTWARE-PIPELINED: jt+1's 4 MFMAs are issued BEFORE jt's results are
// reduced (named A/B tile-sets, no runtime indexing — rule #20), so the
// ~70-cyc packed-min reduction hides MFMA latency in-wave (R12-R14 showed
// the kernel is dependency-latency-bound: immediate consumption stalled
// every jt regardless of occupancy). Rolled j2 loop keeps code/VGPR bounded.
__global__ __launch_bounds__(256) void chamfer_mfma(
        const uint4* __restrict__ Aform, const uint4* __restrict__ Bform,
        unsigned short* __restrict__ part) {
    int bid = blockIdx.x;
    int js  = bid & (JSTR - 1);        // fastest: consecutive blocks share A panel
    int r   = bid >> 5;
    int is4 = r & 15; r >>= 4;
    int b   = r & 3;
    int dir = r >> 2;                  // 0: minimize over pred; 1: over gt
    int Acl = dir;                     // A-side cloud (rows, minimized over)
    int Bcl = dir ^ 1;                 // B-side cloud (cols, output)

    int w    = threadIdx.x >> 6;
    int lane = threadIdx.x & 63;
    int is   = is4 * 4 + w;

    // Stage the block's shared B-tile: 8 fragments x 64 lanes x 16B = 8 KB.
    __shared__ uint4 sb[JT * 64];
    const uint4* bblk = Bform + (((size_t)Bcl * B + b) * 256 + js * JT) * 64;
    sb[threadIdx.x]       = bblk[threadIdx.x];
    sb[threadIdx.x + 256] = bblk[threadIdx.x + 256];

    // Per-wave A fragments (issued before the barrier to overlap latency).
    const uint4* ablk = Aform + (((size_t)Acl * B + b) * 256 + is * IB) * 64 + lane;
    s16x8 a0 = __builtin_bit_cast(s16x8, ablk[0]);
    s16x8 a1 = __builtin_bit_cast(s16x8, ablk[64]);
    s16x8 a2 = __builtin_bit_cast(s16x8, ablk[128]);
    s16x8 a3 = __builtin_bit_cast(s16x8, ablk[192]);

    __syncthreads();

    unsigned short* po = part + (((size_t)dir * B + b) * ISTR + is) * N + js * JT * 32;
    const f32x16 zc = {};
    const uint4* sbl = sb + lane;

    // Prologue: jt=0 tiles in flight as set A.
    s16x8 bf = __builtin_bit_cast(s16x8, sbl[0]);
    f32x16 A0 = __builtin_amdgcn_mfma_f32_32x32x16_bf16(a0, bf, zc, 0, 0, 0);
    f32x16 A1 = __builtin_amdgcn_mfma_f32_32x32x16_bf16(a1, bf, zc, 0, 0, 0);
    f32x16 A2 = __builtin_amdgcn_mfma_f32_32x32x16_bf16(a2, bf, zc, 0, 0, 0);
    f32x16 A3 = __builtin_amdgcn_mfma_f32_32x32x16_bf16(a3, bf, zc, 0, 0, 0);

#pragma unroll 1
    for (int j2 = 0; j2 < JT / 2 - 1; ++j2) {   // covers jt = 0..JT-3
        int jt = 2 * j2;
        s16x8 b1 = __builtin_bit_cast(s16x8, sbl[(size_t)(jt + 1) * 64]);
        f32x16 B0 = __builtin_amdgcn_mfma_f32_32x32x16_bf16(a0, b1, zc, 0, 0, 0);
        f32x16 B1 = __builtin_amdgcn_mfma_f32_32x32x16_bf16(a1, b1, zc, 0, 0, 0);
        f32x16 B2 = __builtin_amdgcn_mfma_f32_32x32x16_bf16(a2, b1, zc, 0, 0, 0);
        f32x16 B3 = __builtin_amdgcn_mfma_f32_32x32x16_bf16(a3, b1, zc, 0, 0, 0);
        REDUCE_STORE(A0, A1, A2, A3, jt);          // overlaps B-set MFMAs
        s16x8 b2 = __builtin_bit_cast(s16x8, sbl[(size_t)(jt + 2) * 64]);
        A0 = __builtin_amdgcn_mfma_f32_32x32x16_bf16(a0, b2, zc, 0, 0, 0);
        A1 = __builtin_amdgcn_mfma_f32_32x32x16_bf16(a1, b2, zc, 0, 0, 0);
        A2 = __builtin_amdgcn_mfma_f32_32x32x16_bf16(a2, b2, zc, 0, 0, 0);
        A3 = __builtin_amdgcn_mfma_f32_32x32x16_bf16(a3, b2, zc, 0, 0, 0);
        REDUCE_STORE(B0, B1, B2, B3, jt + 1);      // overlaps A-set MFMAs
    }
    {   // Tail: A holds jt=JT-2; compute jt=JT-1 as B.
        s16x8 bl = __builtin_bit_cast(s16x8, sbl[(size_t)(JT - 1) * 64]);
        f32x16 B0 = __builtin_amdgcn_mfma_f32_32x32x16_bf16(a0, bl, zc, 0, 0, 0);
        f32x16 B1 = __builtin_amdgcn_mfma_f32_32x32x16_bf16(a1, bl, zc, 0, 0, 0);
        f32x16 B2 = __builtin_amdgcn_mfma_f32_32x32x16_bf16(a2, bl, zc, 0, 0, 0);
        f32x16 B3 = __builtin_amdgcn_mfma_f32_32x32x16_bf16(a3, bl, zc, 0, 0, 0);
        REDUCE_STORE(A0, A1, A2, A3, JT - 2);
        REDUCE_STORE(B0, B1, B2, B3, JT - 1);
    }
}

// 256 blocks: seg = bk>>5; min over 64 i-strips -> block sum/max partials.
__global__ __launch_bounds__(256) void reduce1(
        const unsigned short* __restrict__ part,
        float* __restrict__ bsum, float* __restrict__ bmax) {
    int bk  = blockIdx.x;
    int seg = bk >> 5;                 // 0..7
    int idx = (bk & 31) * 256 + threadIdx.x;
    const unsigned short* base = part + (size_t)seg * ISTR * N + idx;
    float v = FLT_MAX;
#pragma unroll 8
    for (int s = 0; s < ISTR; ++s)
        v = fminf(v, bf2f(base[(size_t)s * N]));
    __shared__ float ssum[256], smax[256];
    ssum[threadIdx.x] = v;
    smax[threadIdx.x] = v;
    __syncthreads();
    for (int st = 128; st > 0; st >>= 1) {
        if (threadIdx.x < st) {
            ssum[threadIdx.x] += ssum[threadIdx.x + st];
            smax[threadIdx.x] = fmaxf(smax[threadIdx.x], smax[threadIdx.x + st]);
        }
        __syncthreads();
    }
    if (threadIdx.x == 0) { bsum[bk] = ssum[0]; bmax[bk] = smax[0]; }
}

// Combine 256 block partials. Blocks [seg*32, seg*32+32) belong to segment seg.
__global__ __launch_bounds__(256) void final_combine(
        const float* __restrict__ bsum, const float* __restrict__ bmax,
        float* __restrict__ out) {
    int t = threadIdx.x;
    __shared__ float ss[256], sm[256];
    ss[t] = bsum[t];
    sm[t] = bmax[t];
    __syncthreads();
    for (int st = 128; st > 0; st >>= 1) {
        if (t < st) ss[t] += ss[t + st];
        __syncthreads();
    }
    for (int st = 16; st > 0; st >>= 1) {
        if ((t & 31) < st) sm[t] = fmaxf(sm[t], sm[t + st]);
        __syncthreads();
    }
    if (t == 0) {
        float hsum = 0.f;
#pragma unroll
        for (int k = 0; k < NSEG; ++k) hsum += sm[k * 32];
        out[0] = ss[0] / (float)(B * N);   // chamfer
        out[1] = hsum / (float)B;          // hausdorff
    }
}

extern "C" void kernel_launch(void* const* d_in, const int* in_sizes, int n_in,
                              void* d_out, int out_size, void* d_ws, size_t ws_size,
                              hipStream_t stream) {
    const float* pred = (const float*)d_in[0];
    const float* gt   = (const float*)d_in[1];
    float* out = (float*)d_out;

    char* p = (char*)d_ws;
    uint4* Aform = (uint4*)p;  p += (size_t)2 * B * 256 * 64 * 16;   // 2 MB
    uint4* Bform = (uint4*)p;  p += (size_t)2 * B * 256 * 64 * 16;   // 2 MB
    unsigned short* part = (unsigned short*)p;
    p += (size_t)2 * B * ISTR * N * 2;                               // 16 MB
    float* bsum = (float*)p;   p += 256 * 4;
    float* bmax = (float*)p;

    pack_kernel<<<512, 256, 0, stream>>>(pred, gt, Aform, Bform);
    // blocks: dir(2) x b(4) x is4(16) x js(32) = 4096, 4 waves each
    chamfer_mfma<<<4096, 256, 0, stream>>>(Aform, Bform, part);
    reduce1<<<256, 256, 0, stream>>>(part, bsum, bmax);
    final_combine<<<1, 256, 0, stream>>>(bsum, bmax, out);
}